// Round 3
// baseline (5035.382 us; speedup 1.0000x reference)
//
#include <hip/hip_runtime.h>
#include <math.h>

#define BB     32
#define DD     768
#define DIi    1536
#define DCONVi 1792
#define NHi    8
#define HDi    192
#define DSi    128
#define NCi    100
#define RIN    3336
#define NLAYER 12
#define NBLK   1024
#define NTHR   256

static __device__ __forceinline__ float siluf(float x) { return x / (1.0f + expf(-x)); }

// ---------------- grid barrier: release-arrive, RELAXED poll, one acquire ----
static __device__ __forceinline__ void gbar(unsigned* bar, int i) {
  __syncthreads();
  if (threadIdx.x == 0) {
    __hip_atomic_fetch_add(bar + i, 1u, __ATOMIC_RELEASE, __HIP_MEMORY_SCOPE_AGENT);
    while (__hip_atomic_load(bar + i, __ATOMIC_RELAXED, __HIP_MEMORY_SCOPE_AGENT) <
           (unsigned)NBLK) {
      __builtin_amdgcn_s_sleep(8);
    }
    (void)__hip_atomic_load(bar + i, __ATOMIC_ACQUIRE, __HIP_MEMORY_SCOPE_AGENT);
  }
  __syncthreads();
}

// ---------------- shared-memory union ---------------------------------------
struct SmConv { float Wl[16][32][5]; float Il[16][32][10]; };       // 30720 B
struct SmInp  { float Wl[64][64];    float Tl[64][36]; };           // 25600 B
struct SmSsm  { float Cl[DSi], Bl[DSi], pl[DSi], xhl[64], zsl[64];
                float s_dt, s_dA, s_coef, sqw[4]; };
struct SmOut  { float Wl[2][64][20]; float Gl[2][64][36]; float sl[2][32]; }; // 28928 B
struct SmFin  { float tl[DD], hl[DD], red1[4], red2[4]; };
union SmAll { SmConv c; SmInp i; SmSsm s; SmOut o; SmFin f; };

// ---------------- phase: patch embed → cin0 [l][b][d] ------------------------
static __device__ void phase_patch(const float* __restrict__ x, const float* __restrict__ pw,
                                   const float* __restrict__ pb, const float* __restrict__ cst0,
                                   float* __restrict__ cin0) {
  for (int idx = blockIdx.x * NTHR + threadIdx.x; idx < 10 * BB * DD; idx += NBLK * NTHR) {
    int d = idx % DD;
    int b = (idx / DD) % BB;
    int l = idx / (DD * BB);
    float v;
    if (l < 4) {
      v = cst0[(b * DD + d) * 4 + l];
    } else {
      int w = l - 4;
      float acc = pb[d];
#pragma unroll
      for (int p = 0; p < 16; p++) acc += x[b * 96 + p * 6 + w] * pw[d * 16 + p];
      v = acc;
    }
    cin0[idx] = v;
  }
}

// ---------------- phase: conv split-K GEMM ----------------------------------
// vblocks 384 = 24 m-tiles(32 douts) x 16 k-split(48 di). 256 thr.
// cin layout [l][b][d]; part layout [slice][n][d], n = b*LOUT+l.
template <int LIN, int LOUT>
static __device__ void phase_conv(SmConv& s, const float* __restrict__ cin,
                                  const float* __restrict__ w, float* __restrict__ part) {
  const int NN = BB * LOUT;
  int tid = threadIdx.x;
  for (int v = blockIdx.x; v < 384; v += NBLK) {
    int bx = v % 24, by = v / 24;
    int m0 = bx * 32, di0 = by * 48;
    int tm = tid >> 4, tb = tid & 15;
    float acc[2][2][LOUT] = {};
    for (int cc = 0; cc < 3; cc++) {
      int dib = di0 + cc * 16;
      {  // stage weights: Wl[di][m][k]
        int m = tid >> 3, di8 = tid & 7;
#pragma unroll
        for (int dd = 0; dd < 2; dd++) {
          int di = di8 + 8 * dd;
          const float* wp = w + (size_t)(m0 + m) * (DD * 5) + (dib + di) * 5;
#pragma unroll
          for (int k = 0; k < 5; k++) s.Wl[di][m][k] = wp[k];
        }
      }
#pragma unroll
      for (int j = 0; j < 2; j++) {  // stage input: Il[di][b][l], coalesced over di
        int flat = tid + NTHR * j;
        int di = flat & 15, b = flat >> 4;
#pragma unroll
        for (int l = 0; l < LIN; l++)
          s.Il[di][b][l] = cin[(size_t)l * (BB * DD) + b * DD + dib + di];
      }
      __syncthreads();
#pragma unroll
      for (int di = 0; di < 16; di++) {
        float a0[LIN], a1[LIN], w0[5], w1[5];
#pragma unroll
        for (int l = 0; l < LIN; l++) { a0[l] = s.Il[di][2 * tb][l]; a1[l] = s.Il[di][2 * tb + 1][l]; }
#pragma unroll
        for (int k = 0; k < 5; k++) { w0[k] = s.Wl[di][2 * tm][k]; w1[k] = s.Wl[di][2 * tm + 1][k]; }
#pragma unroll
        for (int l = 0; l < LOUT; l++)
#pragma unroll
          for (int k = 0; k < 5; k++) {
            acc[0][0][l] += w0[k] * a0[l + k];
            acc[0][1][l] += w0[k] * a1[l + k];
            acc[1][0][l] += w1[k] * a0[l + k];
            acc[1][1][l] += w1[k] * a1[l + k];
          }
      }
      __syncthreads();
    }
#pragma unroll
    for (int mm = 0; mm < 2; mm++)
#pragma unroll
      for (int b2 = 0; b2 < 2; b2++)
#pragma unroll
        for (int l = 0; l < LOUT; l++)
          part[((size_t)by * NN + (2 * tb + b2) * LOUT + l) * DD + (m0 + 2 * tm + mm)] =
              acc[mm][b2][l];
  }
}

// ---------------- phase: bias+BN+relu+pool (elementwise, coalesced over d) ---
static __device__ void phase_bnrelu(int LOUT, int PF, const float* __restrict__ part,
                                    const float* __restrict__ cb, const float* __restrict__ bg,
                                    const float* __restrict__ bbeta, const float* __restrict__ rm,
                                    const float* __restrict__ rv, int mode,
                                    float* __restrict__ outp, const float* __restrict__ stn,
                                    const float* __restrict__ pos, const int* __restrict__ pidx) {
  int NN = BB * LOUT;
  int idx = blockIdx.x * NTHR + threadIdx.x;
  if (idx < BB * DD) {
    int d = idx % DD, b = idx / DD;
    float inv = rsqrtf(rv[d] + 1e-5f);
    float vv[6];
    for (int l = 0; l < LOUT; l++) {
      float sum = cb[d];
      for (int ss = 0; ss < 16; ss++) sum += part[((size_t)ss * NN + b * LOUT + l) * DD + d];
      sum = (sum - rm[d]) * inv * bg[d] + bbeta[d];
      vv[l] = fmaxf(sum, 0.0f);
    }
    int LP = LOUT / PF;
    float pm[6];
    for (int lp = 0; lp < LP; lp++) {
      float m = vv[lp * PF];
      for (int j = 1; j < PF; j++) m = fmaxf(m, vv[lp * PF + j]);
      pm[lp] = m;
    }
    if (mode == 0) {
      for (int j = 0; j < 4; j++) outp[(size_t)j * (BB * DD) + b * DD + d] = stn[(b * DD + d) * 4 + j];
      for (int lp = 0; lp < LP; lp++) outp[(size_t)(4 + lp) * (BB * DD) + b * DD + d] = pm[lp];
    } else {
      int clip = min(*pidx, 299);
      outp[b * DD + d] = pm[0] + pos[(1 + clip) * DD + d];
    }
  }
}

// ---------------- phase: in_proj GEMM, vblocks 212 = 53 x 4 ------------------
static __device__ void phase_inproj(SmInp& s, const float* __restrict__ W,
                                    const float* __restrict__ tokrd, const float* __restrict__ dp,
                                    int use_dp, float* __restrict__ tokwr, float* __restrict__ zx,
                                    float* __restrict__ sq) {
  int tid = threadIdx.x;
  if (blockIdx.x == 0 && tid < BB) sq[tid] = 0.0f;  // re-zero for this layer's SSM atomics
  int v = blockIdx.x;
  if (v < 212) {
    int bx = v % 53, by = v / 53;
    int m0 = bx * 64;
    int tm = tid & 31, tb = tid >> 5;  // 32 tm x 2r, 8 tb x 4b
    float acc[2][4] = {};
    for (int c = 0; c < 3; c++) {
      int k0 = by * 192 + c * 64;
#pragma unroll
      for (int j = 0; j < 4; j++) {  // stage W^T: Wl[k][r]
        int flat = tid + NTHR * j;
        int m = flat >> 4, kf = flat & 15;
        float4 w4 = {0.f, 0.f, 0.f, 0.f};
        if (m0 + m < RIN) w4 = *(const float4*)(W + (size_t)(m0 + m) * DD + k0 + kf * 4);
        s.Wl[kf * 4 + 0][m] = w4.x; s.Wl[kf * 4 + 1][m] = w4.y;
        s.Wl[kf * 4 + 2][m] = w4.z; s.Wl[kf * 4 + 3][m] = w4.w;
      }
#pragma unroll
      for (int j = 0; j < 2; j++) {  // stage tok (+ lazy residual fold)
        int flat = tid + NTHR * j;
        int b = flat >> 4, kf = flat & 15;
        int off = b * DD + k0 + kf * 4;
        float4 t4 = *(const float4*)(tokrd + off);
        if (use_dp) {
#pragma unroll
          for (int ss = 0; ss < 4; ss++) {
            float4 d4 = *(const float4*)(dp + (size_t)ss * (BB * DD) + off);
            t4.x += d4.x; t4.y += d4.y; t4.z += d4.z; t4.w += d4.w;
          }
          if (bx == by) *(float4*)(tokwr + off) = t4;
        }
        s.Tl[kf * 4 + 0][b] = t4.x; s.Tl[kf * 4 + 1][b] = t4.y;
        s.Tl[kf * 4 + 2][b] = t4.z; s.Tl[kf * 4 + 3][b] = t4.w;
      }
      __syncthreads();
#pragma unroll 4
      for (int kk = 0; kk < 64; kk++) {
        float2 wv = *(const float2*)&s.Wl[kk][2 * tm];
        float4 tv = *(const float4*)&s.Tl[kk][4 * tb];
        acc[0][0] += wv.x * tv.x; acc[0][1] += wv.x * tv.y;
        acc[0][2] += wv.x * tv.z; acc[0][3] += wv.x * tv.w;
        acc[1][0] += wv.y * tv.x; acc[1][1] += wv.y * tv.y;
        acc[1][2] += wv.y * tv.z; acc[1][3] += wv.y * tv.w;
      }
      __syncthreads();
    }
#pragma unroll
    for (int mm = 0; mm < 2; mm++)
#pragma unroll
      for (int b2 = 0; b2 < 4; b2++) {
        int r = m0 + 2 * tm + mm;
        if (r < RIN) zx[((size_t)by * BB + 4 * tb + b2) * RIN + r] = acc[mm][b2];
      }
  }
}

// ---------------- phase: SSM, vblocks 768 = b x h x pchunk -------------------
static __device__ void phase_ssm(SmSsm& sm, const float* __restrict__ zx,
                                 const float* __restrict__ ssm, const float* __restrict__ cst,
                                 const float* __restrict__ cw, const float* __restrict__ cb,
                                 const float* __restrict__ alog, const float* __restrict__ dtb,
                                 const float* __restrict__ dpar, float* __restrict__ y,
                                 float* __restrict__ sq) {
  int tid = threadIdx.x;
  for (int v = blockIdx.x; v < 768; v += NBLK) {
    int b = v / 24;
    int rem = v % 24;
    int h = rem / 3;
    int p0 = (rem % 3) * 64;

    auto convgate = [&](int c) -> float {
      float zr = 0.f;
#pragma unroll
      for (int s = 0; s < 4; s++) zr += zx[(size_t)s * (BB * RIN) + b * RIN + (DIi + c)];
      float4 c4 = *(const float4*)(cst + (size_t)(b * DCONVi + c) * 4);
      float4 w4 = *(const float4*)(cw + (size_t)c * 4);
      float val = c4.y * w4.x + c4.z * w4.y + c4.w * w4.z + zr * w4.w + cb[c];
      return siluf(val);
    };

    if (tid < 128) sm.Cl[tid] = convgate(DIi + DSi + tid);
    else sm.Bl[tid - 128] = convgate(DIi + (tid - 128));
    __syncthreads();
    if (tid < 128) {
      sm.pl[tid] = sm.Bl[tid] * sm.Cl[tid];
    } else if (tid < 192) {
      int p = tid - 128;
      sm.xhl[p] = convgate(h * HDi + p0 + p);
    } else {
      int p = tid - 192;
      float zr = 0.f;
#pragma unroll
      for (int s = 0; s < 4; s++)
        zr += zx[(size_t)s * (BB * RIN) + b * RIN + (h * HDi + p0 + p)];
      sm.zsl[p] = siluf(zr);
    }
    if (tid == 0) {
      float zr = 0.f;
#pragma unroll
      for (int s = 0; s < 4; s++)
        zr += zx[(size_t)s * (BB * RIN) + b * RIN + (DIi + DCONVi + h)];
      float xdt = zr + dtb[h];
      float dt = fmaxf(xdt, 0.f) + log1pf(expf(-fabsf(xdt)));
      sm.s_dt = dt;
      sm.s_dA = expf(-expf(alog[h]) * dt);
    }
    __syncthreads();
    if (tid < 64) {
      float pv = sm.pl[tid] + sm.pl[tid + 64];
#pragma unroll
      for (int m = 1; m < 64; m <<= 1) pv += __shfl_xor(pv, m, 64);
      if (tid == 0) sm.s_coef = sm.s_dt * pv + dpar[h];
    }
    __syncthreads();

    float dA = sm.s_dA, coef = sm.s_coef;
    int wv = tid >> 6, lane = tid & 63;
    float c0 = sm.Cl[2 * lane], c1 = sm.Cl[2 * lane + 1];
    int pw = p0 + wv * 16;
    const float* sb = ssm + (size_t)((b * NHi + h) * HDi + pw) * DSi + 2 * lane;
    float acc[16];
#pragma unroll
    for (int i = 0; i < 16; i++) {  // 16 independent loads in flight
      float2 sv = *(const float2*)(sb + (size_t)i * DSi);
      acc[i] = sv.x * c0 + sv.y * c1;
    }
#pragma unroll
    for (int m = 1; m < 64; m <<= 1) {  // interleaved butterfly: 16 indep chains
#pragma unroll
      for (int i = 0; i < 16; i++) acc[i] += __shfl_xor(acc[i], m, 64);
    }
    if (lane == 0) {
      float gs = 0.f;
#pragma unroll
      for (int i = 0; i < 16; i++) {
        float yv = dA * acc[i] + coef * sm.xhl[pw - p0 + i];
        y[b * DIi + h * HDi + pw + i] = yv;
        float g = yv * sm.zsl[pw - p0 + i];
        gs += g * g;
      }
      sm.sqw[wv] = gs;
    }
    __syncthreads();
    if (tid == 0) atomicAdd(&sq[b], sm.sqw[0] + sm.sqw[1] + sm.sqw[2] + sm.sqw[3]);
  }
}

// ---------------- phase: out_proj GEMM, vblocks 192, 2 sub-blocks ------------
static __device__ void phase_outproj(SmOut& s, const float* __restrict__ W,
                                     const float* __restrict__ y, const float* __restrict__ zx,
                                     const float* __restrict__ sq, const float* __restrict__ nw,
                                     float* __restrict__ dp) {
  if (blockIdx.x >= 96) return;
  int sub = threadIdx.x >> 7, tid = threadIdx.x & 127;
  int vb = blockIdx.x * 2 + sub;
  int bx = vb % 48, by = vb / 48;
  if (tid < BB) s.sl[sub][tid] = rsqrtf(sq[tid] * (1.0f / (float)DIi) + 1e-5f);
  __syncthreads();
  int m0 = bx * 16;
  int tm = tid & 7, tb = tid >> 3;
  float acc[2][2] = {};
  for (int c = 0; c < 6; c++) {
    int k0 = by * 384 + c * 64;
#pragma unroll
    for (int j = 0; j < 2; j++) {
      int flat = tid + 128 * j;
      int m = flat >> 4, kf = flat & 15;
      float4 w4 = *(const float4*)(W + (size_t)(m0 + m) * DIi + k0 + kf * 4);
      s.Wl[sub][kf * 4 + 0][m] = w4.x; s.Wl[sub][kf * 4 + 1][m] = w4.y;
      s.Wl[sub][kf * 4 + 2][m] = w4.z; s.Wl[sub][kf * 4 + 3][m] = w4.w;
    }
#pragma unroll
    for (int j = 0; j < 4; j++) {
      int flat = tid + 128 * j;
      int b = flat >> 4, kf = flat & 15;
      int k = k0 + kf * 4;
      float4 y4 = *(const float4*)(y + b * DIi + k);
      float4 z4 = {0.f, 0.f, 0.f, 0.f};
#pragma unroll
      for (int ss = 0; ss < 4; ss++) {
        float4 t = *(const float4*)(zx + (size_t)ss * (BB * RIN) + b * RIN + k);
        z4.x += t.x; z4.y += t.y; z4.z += t.z; z4.w += t.w;
      }
      float4 n4 = *(const float4*)(nw + k);
      float sc = s.sl[sub][b];
      s.Gl[sub][kf * 4 + 0][b] = y4.x * siluf(z4.x) * sc * n4.x;
      s.Gl[sub][kf * 4 + 1][b] = y4.y * siluf(z4.y) * sc * n4.y;
      s.Gl[sub][kf * 4 + 2][b] = y4.z * siluf(z4.z) * sc * n4.z;
      s.Gl[sub][kf * 4 + 3][b] = y4.w * siluf(z4.w) * sc * n4.w;
    }
    __syncthreads();
#pragma unroll 4
    for (int kk = 0; kk < 64; kk++) {
      float2 w2 = *(const float2*)&s.Wl[sub][kk][2 * tm];
      float2 g2 = *(const float2*)&s.Gl[sub][kk][2 * tb];
      acc[0][0] += w2.x * g2.x; acc[0][1] += w2.x * g2.y;
      acc[1][0] += w2.y * g2.x; acc[1][1] += w2.y * g2.y;
    }
    __syncthreads();
  }
#pragma unroll
  for (int mm = 0; mm < 2; mm++)
#pragma unroll
    for (int b2 = 0; b2 < 2; b2++)
      dp[((size_t)by * BB + 2 * tb + b2) * DD + m0 + 2 * tm + mm] = acc[mm][b2];
}

// ---------------- phase: final LN + history + logits -------------------------
static __device__ void phase_final(SmFin& s, const float* __restrict__ tok,
                                   const float* __restrict__ dp, const float* __restrict__ hf,
                                   const float* __restrict__ fg, const float* __restrict__ fb,
                                   const float* __restrict__ fcw, const float* __restrict__ fcb,
                                   const int* __restrict__ pidx, float* __restrict__ out) {
  if (blockIdx.x >= BB) return;
  int b = blockIdx.x, tid = threadIdx.x;
  int wv = tid >> 6, lane = tid & 63;
  float psum = 0.f;
  for (int d = tid; d < DD; d += NTHR) {
    float v = tok[b * DD + d];
#pragma unroll
    for (int ss = 0; ss < 4; ss++) v += dp[(size_t)ss * (BB * DD) + b * DD + d];
    s.tl[d] = v;
    psum += v;
  }
#pragma unroll
  for (int m = 1; m < 64; m <<= 1) psum += __shfl_xor(psum, m, 64);
  if (lane == 0) s.red1[wv] = psum;
  __syncthreads();
  float mu = (s.red1[0] + s.red1[1] + s.red1[2] + s.red1[3]) * (1.0f / (float)DD);
  float vsum = 0.f;
  for (int d = tid; d < DD; d += NTHR) {
    float dd = s.tl[d] - mu;
    vsum += dd * dd;
  }
#pragma unroll
  for (int m = 1; m < 64; m <<= 1) vsum += __shfl_xor(vsum, m, 64);
  if (lane == 0) s.red2[wv] = vsum;
  __syncthreads();
  float var = (s.red2[0] + s.red2[1] + s.red2[2] + s.red2[3]) * (1.0f / (float)DD);
  float inv = rsqrtf(var + 1e-5f);
  float pi = (float)(*pidx);
  for (int d = tid; d < DD; d += NTHR) {
    float tn = (s.tl[d] - mu) * inv * fg[d] + fb[d];
    float hv = (hf[b * DD + d] * pi + tn) / (pi + 1.0f);
    s.hl[d] = hv;
    out[BB * NCi + b * DD + d] = hv;
  }
  __syncthreads();
  for (int n = wv; n < NCi; n += 4) {
    float sum = 0.f;
    for (int d = lane; d < DD; d += 64) sum += s.hl[d] * fcw[(size_t)n * DD + d];
#pragma unroll
    for (int m = 1; m < 64; m <<= 1) sum += __shfl_xor(sum, m, 64);
    if (lane == 0) out[b * NCi + n] = sum + fcb[n];
  }
}

// ---------------- init: zero barrier slots ----------------------------------
__global__ void k_zero(unsigned* bar) {
  if (threadIdx.x < 64) bar[threadIdx.x] = 0u;
}

// ---------------- the mega-kernel -------------------------------------------
__global__ __launch_bounds__(NTHR, 4) void k_mega(
    const float* x, const float* hf, const float* patch_w, const float* patch_b,
    const float* cnn_w, const float* cnn_b, const float* bn_g, const float* bn_b,
    const float* bn_rm, const float* bn_rv, const float* cnn_st, const float* pos,
    const float* ipw, const float* cw, const float* cb1, const float* alog, const float* dtb,
    const float* dpar, const float* nw, const float* opw, const float* mcs, const float* ssm,
    const float* fcn_g, const float* fcn_b, const float* fc_w, const float* fc_b,
    const int* pidx, float* out, float* cin0, float* cin1, float* cin2, float* cin3,
    float* part, float* t0, float* t1, float* zx, float* yb, float* sq, float* dp,
    unsigned* bar) {
  __shared__ SmAll sm;

  phase_patch(x, patch_w, patch_b, cnn_st, cin0);
  gbar(bar, 0);
  phase_conv<10, 6>(sm.c, cin0, cnn_w + (size_t)0 * DD * DD * 5, part);
  gbar(bar, 1);
  phase_bnrelu(6, 1, part, cnn_b, bn_g, bn_b, bn_rm, bn_rv, 0, cin1,
               cnn_st + (size_t)1 * BB * DD * 4, pos, pidx);
  gbar(bar, 2);
  phase_conv<10, 6>(sm.c, cin1, cnn_w + (size_t)1 * DD * DD * 5, part);
  gbar(bar, 3);
  phase_bnrelu(6, 3, part, cnn_b + DD, bn_g + DD, bn_b + DD, bn_rm + DD, bn_rv + DD, 0, cin2,
               cnn_st + (size_t)2 * BB * DD * 4, pos, pidx);
  gbar(bar, 4);
  phase_conv<6, 2>(sm.c, cin2, cnn_w + (size_t)2 * DD * DD * 5, part);
  gbar(bar, 5);
  phase_bnrelu(2, 1, part, cnn_b + 2 * DD, bn_g + 2 * DD, bn_b + 2 * DD, bn_rm + 2 * DD,
               bn_rv + 2 * DD, 0, cin3, cnn_st + (size_t)3 * BB * DD * 4, pos, pidx);
  gbar(bar, 6);
  phase_conv<6, 2>(sm.c, cin3, cnn_w + (size_t)3 * DD * DD * 5, part);
  gbar(bar, 7);
  phase_bnrelu(2, 2, part, cnn_b + 3 * DD, bn_g + 3 * DD, bn_b + 3 * DD, bn_rm + 3 * DD,
               bn_rv + 3 * DD, 1, t0, nullptr, pos, pidx);
  gbar(bar, 8);

  int bi = 9;
  for (int L = 0; L < NLAYER; L++) {
    const float* rd = (L == 0) ? t0 : ((L & 1) ? t0 : t1);
    float* wr = (L & 1) ? t1 : ((L == 0) ? t1 : t0);
    phase_inproj(sm.i, ipw + (size_t)L * RIN * DD, rd, dp, (L > 0) ? 1 : 0, wr, zx, sq);
    gbar(bar, bi++);
    phase_ssm(sm.s, zx, ssm + (size_t)L * BB * NHi * HDi * DSi, mcs + (size_t)L * BB * DCONVi * 4,
              cw + (size_t)L * DCONVi * 4, cb1 + (size_t)L * DCONVi, alog + L * NHi,
              dtb + L * NHi, dpar + L * NHi, yb, sq);
    gbar(bar, bi++);
    phase_outproj(sm.o, opw + (size_t)L * DD * DIi, yb, zx, sq, nw + (size_t)L * DIi, dp);
    gbar(bar, bi++);
  }
  phase_final(sm.f, t1, dp, hf, fcn_g, fcn_b, fc_w, fc_b, pidx, out);
}

// ---------------------------------------------------------------------------
extern "C" void kernel_launch(void* const* d_in, const int* in_sizes, int n_in,
                              void* d_out, int out_size, void* d_ws, size_t ws_size,
                              hipStream_t stream) {
  const float* x       = (const float*)d_in[0];
  const float* hf      = (const float*)d_in[1];
  const float* patch_w = (const float*)d_in[2];
  const float* patch_b = (const float*)d_in[3];
  const float* cnn_w   = (const float*)d_in[4];
  const float* cnn_b   = (const float*)d_in[5];
  const float* bn_g    = (const float*)d_in[6];
  const float* bn_b    = (const float*)d_in[7];
  const float* bn_rm   = (const float*)d_in[8];
  const float* bn_rv   = (const float*)d_in[9];
  const float* cnn_st  = (const float*)d_in[10];
  const float* pos     = (const float*)d_in[11];
  const float* ipw     = (const float*)d_in[12];
  const float* cw      = (const float*)d_in[13];
  const float* cb1     = (const float*)d_in[14];
  const float* alog    = (const float*)d_in[15];
  const float* dtb     = (const float*)d_in[16];
  const float* dpar    = (const float*)d_in[17];
  const float* nw      = (const float*)d_in[18];
  const float* opw     = (const float*)d_in[19];
  const float* mcs     = (const float*)d_in[20];
  const float* ssm     = (const float*)d_in[21];
  const float* fcn_g   = (const float*)d_in[22];
  const float* fcn_b   = (const float*)d_in[23];
  const float* fc_w    = (const float*)d_in[24];
  const float* fc_b    = (const float*)d_in[25];
  const int*   pidx    = (const int*)d_in[26];
  float* out = (float*)d_out;

  unsigned* bar = (unsigned*)d_ws;
  float* fw   = (float*)d_ws + 64;
  float* cin0 = fw;                  // 10*32*768 = 245760
  float* cin1 = cin0 + 245760;       // 245760
  float* cin2 = cin1 + 245760;       // 6*32*768 = 147456
  float* cin3 = cin2 + 147456;       // 147456
  float* part = cin3 + 147456;       // 16*192*768 = 2359296
  float* t0   = part + 2359296;      // 24576
  float* t1   = t0 + 24576;          // 24576
  float* zx   = t1 + 24576;          // 4*32*3336 = 427008
  float* yb   = zx + 427008;         // 49152
  float* sq   = yb + 49152;          // 32
  float* dp   = sq + 32;             // 4*32*768 = 98304

  k_zero<<<1, 64, 0, stream>>>(bar);
  k_mega<<<NBLK, NTHR, 0, stream>>>(x, hf, patch_w, patch_b, cnn_w, cnn_b, bn_g, bn_b, bn_rm,
                                    bn_rv, cnn_st, pos, ipw, cw, cb1, alog, dtb, dpar, nw, opw,
                                    mcs, ssm, fcn_g, fcn_b, fc_w, fc_b, pidx, out, cin0, cin1,
                                    cin2, cin3, part, t0, t1, zx, yb, sq, dp, bar);
}

// Round 4
// 2865.665 us; speedup vs baseline: 1.7571x; 1.7571x over previous
//
#include <hip/hip_runtime.h>
#include <math.h>

#define BB     32
#define DD     768
#define DIi    1536
#define DCONVi 1792
#define NHi    8
#define HDi    192
#define DSi    128
#define NCi    100
#define RIN    3336
#define NLAYER 12
#define NBLK   512
#define NTHR   256

// tree barrier geometry
#define GSIZE  16
#define NGRP   (NBLK / GSIZE)            // 32
#define BSTRIDE ((1 + 2 * NGRP) * 16)    // uints per barrier (each slot on own 64B line)
#define NBAR   45

static __device__ __forceinline__ float siluf(float x) { return x / (1.0f + expf(-x)); }

// ---------------- tree grid barrier -----------------------------------------
// Arrivals: acq_rel adds into per-group lines (16 each) -> group-last acq_rel
// add to root -> global-last release-stores 32 go flags. Members relaxed-poll
// their group's flag (<=16 pollers/line), one acquire at exit.
static __device__ __forceinline__ void gbar(unsigned* bar, int i) {
  __syncthreads();
  if (threadIdx.x == 0) {
    unsigned* base = bar + (size_t)i * BSTRIDE;
    int g = blockIdx.x / GSIZE;
    unsigned* gcnt = base + (size_t)(1 + g) * 16;
    unsigned* ggo  = base + (size_t)(1 + NGRP + g) * 16;
    unsigned r = __hip_atomic_fetch_add(gcnt, 1u, __ATOMIC_ACQ_REL, __HIP_MEMORY_SCOPE_AGENT);
    if (r == GSIZE - 1) {
      unsigned rr = __hip_atomic_fetch_add(base, 1u, __ATOMIC_ACQ_REL, __HIP_MEMORY_SCOPE_AGENT);
      if (rr == NGRP - 1) {
        for (int gg = 0; gg < NGRP; gg++)
          __hip_atomic_store(base + (size_t)(1 + NGRP + gg) * 16, 1u, __ATOMIC_RELEASE,
                             __HIP_MEMORY_SCOPE_AGENT);
      }
    }
    while (__hip_atomic_load(ggo, __ATOMIC_RELAXED, __HIP_MEMORY_SCOPE_AGENT) == 0u)
      __builtin_amdgcn_s_sleep(16);
    (void)__hip_atomic_load(ggo, __ATOMIC_ACQUIRE, __HIP_MEMORY_SCOPE_AGENT);
  }
  __syncthreads();
}

// ---------------- shared-memory union ---------------------------------------
struct SmConv { float Wl[16][32][5]; float Il[16][32][10]; };       // 30720 B
struct SmInp  { float Wl[64][64];    float Tl[64][36]; };           // 25600 B
struct SmSsm  { float Cl[DSi], Bl[DSi], pl[DSi], xhl[64], zsl[64];
                float s_dt, s_dA, s_coef, sqw[4]; };
struct SmOut  { float Wl[2][64][20]; float Gl[2][64][36]; float sl[2][32]; }; // 28928 B
struct SmFin  { float tl[DD], hl[DD], red1[4], red2[4]; };
union SmAll { SmConv c; SmInp i; SmSsm s; SmOut o; SmFin f; };

// ---------------- phase: patch embed → cin0 [l][b][d] ------------------------
static __device__ void phase_patch(const float* __restrict__ x, const float* __restrict__ pw,
                                   const float* __restrict__ pb, const float* __restrict__ cst0,
                                   float* __restrict__ cin0) {
  for (int idx = blockIdx.x * NTHR + threadIdx.x; idx < 10 * BB * DD; idx += NBLK * NTHR) {
    int d = idx % DD;
    int b = (idx / DD) % BB;
    int l = idx / (DD * BB);
    float v;
    if (l < 4) {
      v = cst0[(b * DD + d) * 4 + l];
    } else {
      int w = l - 4;
      float acc = pb[d];
#pragma unroll
      for (int p = 0; p < 16; p++) acc += x[b * 96 + p * 6 + w] * pw[d * 16 + p];
      v = acc;
    }
    cin0[idx] = v;
  }
}

// ---------------- phase: conv split-K GEMM ----------------------------------
template <int LIN, int LOUT>
static __device__ void phase_conv(SmConv& s, const float* __restrict__ cin,
                                  const float* __restrict__ w, float* __restrict__ part) {
  const int NN = BB * LOUT;
  int tid = threadIdx.x;
  for (int v = blockIdx.x; v < 384; v += NBLK) {
    int bx = v % 24, by = v / 24;
    int m0 = bx * 32, di0 = by * 48;
    int tm = tid >> 4, tb = tid & 15;
    float acc[2][2][LOUT] = {};
    for (int cc = 0; cc < 3; cc++) {
      int dib = di0 + cc * 16;
      {
        int m = tid >> 3, di8 = tid & 7;
#pragma unroll
        for (int dd = 0; dd < 2; dd++) {
          int di = di8 + 8 * dd;
          const float* wp = w + (size_t)(m0 + m) * (DD * 5) + (dib + di) * 5;
#pragma unroll
          for (int k = 0; k < 5; k++) s.Wl[di][m][k] = wp[k];
        }
      }
#pragma unroll
      for (int j = 0; j < 2; j++) {
        int flat = tid + NTHR * j;
        int di = flat & 15, b = flat >> 4;
#pragma unroll
        for (int l = 0; l < LIN; l++)
          s.Il[di][b][l] = cin[(size_t)l * (BB * DD) + b * DD + dib + di];
      }
      __syncthreads();
#pragma unroll
      for (int di = 0; di < 16; di++) {
        float a0[LIN], a1[LIN], w0[5], w1[5];
#pragma unroll
        for (int l = 0; l < LIN; l++) { a0[l] = s.Il[di][2 * tb][l]; a1[l] = s.Il[di][2 * tb + 1][l]; }
#pragma unroll
        for (int k = 0; k < 5; k++) { w0[k] = s.Wl[di][2 * tm][k]; w1[k] = s.Wl[di][2 * tm + 1][k]; }
#pragma unroll
        for (int l = 0; l < LOUT; l++)
#pragma unroll
          for (int k = 0; k < 5; k++) {
            acc[0][0][l] += w0[k] * a0[l + k];
            acc[0][1][l] += w0[k] * a1[l + k];
            acc[1][0][l] += w1[k] * a0[l + k];
            acc[1][1][l] += w1[k] * a1[l + k];
          }
      }
      __syncthreads();
    }
#pragma unroll
    for (int mm = 0; mm < 2; mm++)
#pragma unroll
      for (int b2 = 0; b2 < 2; b2++)
#pragma unroll
        for (int l = 0; l < LOUT; l++)
          part[((size_t)by * NN + (2 * tb + b2) * LOUT + l) * DD + (m0 + 2 * tm + mm)] =
              acc[mm][b2][l];
  }
}

// ---------------- phase: bias+BN+relu+pool ----------------------------------
static __device__ void phase_bnrelu(int LOUT, int PF, const float* __restrict__ part,
                                    const float* __restrict__ cb, const float* __restrict__ bg,
                                    const float* __restrict__ bbeta, const float* __restrict__ rm,
                                    const float* __restrict__ rv, int mode,
                                    float* __restrict__ outp, const float* __restrict__ stn,
                                    const float* __restrict__ pos, const int* __restrict__ pidx) {
  int NN = BB * LOUT;
  int idx = blockIdx.x * NTHR + threadIdx.x;
  if (idx < BB * DD) {
    int d = idx % DD, b = idx / DD;
    float inv = rsqrtf(rv[d] + 1e-5f);
    float vv[6];
    for (int l = 0; l < LOUT; l++) {
      float sum = cb[d];
      for (int ss = 0; ss < 16; ss++) sum += part[((size_t)ss * NN + b * LOUT + l) * DD + d];
      sum = (sum - rm[d]) * inv * bg[d] + bbeta[d];
      vv[l] = fmaxf(sum, 0.0f);
    }
    int LP = LOUT / PF;
    float pm[6];
    for (int lp = 0; lp < LP; lp++) {
      float m = vv[lp * PF];
      for (int j = 1; j < PF; j++) m = fmaxf(m, vv[lp * PF + j]);
      pm[lp] = m;
    }
    if (mode == 0) {
      for (int j = 0; j < 4; j++) outp[(size_t)j * (BB * DD) + b * DD + d] = stn[(b * DD + d) * 4 + j];
      for (int lp = 0; lp < LP; lp++) outp[(size_t)(4 + lp) * (BB * DD) + b * DD + d] = pm[lp];
    } else {
      int clip = min(*pidx, 299);
      outp[b * DD + d] = pm[0] + pos[(1 + clip) * DD + d];
    }
  }
}

// ---------------- phase: in_proj GEMM ---------------------------------------
static __device__ void phase_inproj(SmInp& s, const float* __restrict__ W,
                                    const float* __restrict__ tokrd, const float* __restrict__ dp,
                                    int use_dp, float* __restrict__ tokwr, float* __restrict__ zx,
                                    float* __restrict__ sq) {
  int tid = threadIdx.x;
  if (blockIdx.x == 0 && tid < BB) sq[tid] = 0.0f;
  int v = blockIdx.x;
  if (v < 212) {
    int bx = v % 53, by = v / 53;
    int m0 = bx * 64;
    int tm = tid & 31, tb = tid >> 5;
    float acc[2][4] = {};
    for (int c = 0; c < 3; c++) {
      int k0 = by * 192 + c * 64;
#pragma unroll
      for (int j = 0; j < 4; j++) {
        int flat = tid + NTHR * j;
        int m = flat >> 4, kf = flat & 15;
        float4 w4 = {0.f, 0.f, 0.f, 0.f};
        if (m0 + m < RIN) w4 = *(const float4*)(W + (size_t)(m0 + m) * DD + k0 + kf * 4);
        s.Wl[kf * 4 + 0][m] = w4.x; s.Wl[kf * 4 + 1][m] = w4.y;
        s.Wl[kf * 4 + 2][m] = w4.z; s.Wl[kf * 4 + 3][m] = w4.w;
      }
#pragma unroll
      for (int j = 0; j < 2; j++) {
        int flat = tid + NTHR * j;
        int b = flat >> 4, kf = flat & 15;
        int off = b * DD + k0 + kf * 4;
        float4 t4 = *(const float4*)(tokrd + off);
        if (use_dp) {
#pragma unroll
          for (int ss = 0; ss < 4; ss++) {
            float4 d4 = *(const float4*)(dp + (size_t)ss * (BB * DD) + off);
            t4.x += d4.x; t4.y += d4.y; t4.z += d4.z; t4.w += d4.w;
          }
          if (bx == by) *(float4*)(tokwr + off) = t4;
        }
        s.Tl[kf * 4 + 0][b] = t4.x; s.Tl[kf * 4 + 1][b] = t4.y;
        s.Tl[kf * 4 + 2][b] = t4.z; s.Tl[kf * 4 + 3][b] = t4.w;
      }
      __syncthreads();
#pragma unroll 4
      for (int kk = 0; kk < 64; kk++) {
        float2 wv = *(const float2*)&s.Wl[kk][2 * tm];
        float4 tv = *(const float4*)&s.Tl[kk][4 * tb];
        acc[0][0] += wv.x * tv.x; acc[0][1] += wv.x * tv.y;
        acc[0][2] += wv.x * tv.z; acc[0][3] += wv.x * tv.w;
        acc[1][0] += wv.y * tv.x; acc[1][1] += wv.y * tv.y;
        acc[1][2] += wv.y * tv.z; acc[1][3] += wv.y * tv.w;
      }
      __syncthreads();
    }
#pragma unroll
    for (int mm = 0; mm < 2; mm++)
#pragma unroll
      for (int b2 = 0; b2 < 4; b2++) {
        int r = m0 + 2 * tm + mm;
        if (r < RIN) zx[((size_t)by * BB + 4 * tb + b2) * RIN + r] = acc[mm][b2];
      }
  }
}

// ---------------- phase: SSM -------------------------------------------------
static __device__ void phase_ssm(SmSsm& sm, const float* __restrict__ zx,
                                 const float* __restrict__ ssm, const float* __restrict__ cst,
                                 const float* __restrict__ cw, const float* __restrict__ cb,
                                 const float* __restrict__ alog, const float* __restrict__ dtb,
                                 const float* __restrict__ dpar, float* __restrict__ y,
                                 float* __restrict__ sq) {
  int tid = threadIdx.x;
  for (int v = blockIdx.x; v < 768; v += NBLK) {
    int b = v / 24;
    int rem = v % 24;
    int h = rem / 3;
    int p0 = (rem % 3) * 64;

    auto convgate = [&](int c) -> float {
      float zr = 0.f;
#pragma unroll
      for (int s = 0; s < 4; s++) zr += zx[(size_t)s * (BB * RIN) + b * RIN + (DIi + c)];
      float4 c4 = *(const float4*)(cst + (size_t)(b * DCONVi + c) * 4);
      float4 w4 = *(const float4*)(cw + (size_t)c * 4);
      float val = c4.y * w4.x + c4.z * w4.y + c4.w * w4.z + zr * w4.w + cb[c];
      return siluf(val);
    };

    if (tid < 128) sm.Cl[tid] = convgate(DIi + DSi + tid);
    else sm.Bl[tid - 128] = convgate(DIi + (tid - 128));
    __syncthreads();
    if (tid < 128) {
      sm.pl[tid] = sm.Bl[tid] * sm.Cl[tid];
    } else if (tid < 192) {
      int p = tid - 128;
      sm.xhl[p] = convgate(h * HDi + p0 + p);
    } else {
      int p = tid - 192;
      float zr = 0.f;
#pragma unroll
      for (int s = 0; s < 4; s++)
        zr += zx[(size_t)s * (BB * RIN) + b * RIN + (h * HDi + p0 + p)];
      sm.zsl[p] = siluf(zr);
    }
    if (tid == 0) {
      float zr = 0.f;
#pragma unroll
      for (int s = 0; s < 4; s++)
        zr += zx[(size_t)s * (BB * RIN) + b * RIN + (DIi + DCONVi + h)];
      float xdt = zr + dtb[h];
      float dt = fmaxf(xdt, 0.f) + log1pf(expf(-fabsf(xdt)));
      sm.s_dt = dt;
      sm.s_dA = expf(-expf(alog[h]) * dt);
    }
    __syncthreads();
    if (tid < 64) {
      float pv = sm.pl[tid] + sm.pl[tid + 64];
#pragma unroll
      for (int m = 1; m < 64; m <<= 1) pv += __shfl_xor(pv, m, 64);
      if (tid == 0) sm.s_coef = sm.s_dt * pv + dpar[h];
    }
    __syncthreads();

    float dA = sm.s_dA, coef = sm.s_coef;
    int wv = tid >> 6, lane = tid & 63;
    float c0 = sm.Cl[2 * lane], c1 = sm.Cl[2 * lane + 1];
    int pw = p0 + wv * 16;
    const float* sb = ssm + (size_t)((b * NHi + h) * HDi + pw) * DSi + 2 * lane;
    float acc[16];
#pragma unroll
    for (int i = 0; i < 16; i++) {
      float2 sv = *(const float2*)(sb + (size_t)i * DSi);
      acc[i] = sv.x * c0 + sv.y * c1;
    }
#pragma unroll
    for (int m = 1; m < 64; m <<= 1) {
#pragma unroll
      for (int i = 0; i < 16; i++) acc[i] += __shfl_xor(acc[i], m, 64);
    }
    if (lane == 0) {
      float gs = 0.f;
#pragma unroll
      for (int i = 0; i < 16; i++) {
        float yv = dA * acc[i] + coef * sm.xhl[pw - p0 + i];
        y[b * DIi + h * HDi + pw + i] = yv;
        float g = yv * sm.zsl[pw - p0 + i];
        gs += g * g;
      }
      sm.sqw[wv] = gs;
    }
    __syncthreads();
    if (tid == 0) atomicAdd(&sq[b], sm.sqw[0] + sm.sqw[1] + sm.sqw[2] + sm.sqw[3]);
    __syncthreads();
  }
}

// ---------------- phase: out_proj GEMM --------------------------------------
static __device__ void phase_outproj(SmOut& s, const float* __restrict__ W,
                                     const float* __restrict__ y, const float* __restrict__ zx,
                                     const float* __restrict__ sq, const float* __restrict__ nw,
                                     float* __restrict__ dp) {
  if (blockIdx.x >= 96) return;
  int sub = threadIdx.x >> 7, tid = threadIdx.x & 127;
  int vb = blockIdx.x * 2 + sub;
  int bx = vb % 48, by = vb / 48;
  if (tid < BB) s.sl[sub][tid] = rsqrtf(sq[tid] * (1.0f / (float)DIi) + 1e-5f);
  __syncthreads();
  int m0 = bx * 16;
  int tm = tid & 7, tb = tid >> 3;
  float acc[2][2] = {};
  for (int c = 0; c < 6; c++) {
    int k0 = by * 384 + c * 64;
#pragma unroll
    for (int j = 0; j < 2; j++) {
      int flat = tid + 128 * j;
      int m = flat >> 4, kf = flat & 15;
      float4 w4 = *(const float4*)(W + (size_t)(m0 + m) * DIi + k0 + kf * 4);
      s.Wl[sub][kf * 4 + 0][m] = w4.x; s.Wl[sub][kf * 4 + 1][m] = w4.y;
      s.Wl[sub][kf * 4 + 2][m] = w4.z; s.Wl[sub][kf * 4 + 3][m] = w4.w;
    }
#pragma unroll
    for (int j = 0; j < 4; j++) {
      int flat = tid + 128 * j;
      int b = flat >> 4, kf = flat & 15;
      int k = k0 + kf * 4;
      float4 y4 = *(const float4*)(y + b * DIi + k);
      float4 z4 = {0.f, 0.f, 0.f, 0.f};
#pragma unroll
      for (int ss = 0; ss < 4; ss++) {
        float4 t = *(const float4*)(zx + (size_t)ss * (BB * RIN) + b * RIN + k);
        z4.x += t.x; z4.y += t.y; z4.z += t.z; z4.w += t.w;
      }
      float4 n4 = *(const float4*)(nw + k);
      float sc = s.sl[sub][b];
      s.Gl[sub][kf * 4 + 0][b] = y4.x * siluf(z4.x) * sc * n4.x;
      s.Gl[sub][kf * 4 + 1][b] = y4.y * siluf(z4.y) * sc * n4.y;
      s.Gl[sub][kf * 4 + 2][b] = y4.z * siluf(z4.z) * sc * n4.z;
      s.Gl[sub][kf * 4 + 3][b] = y4.w * siluf(z4.w) * sc * n4.w;
    }
    __syncthreads();
#pragma unroll 4
    for (int kk = 0; kk < 64; kk++) {
      float2 w2 = *(const float2*)&s.Wl[sub][kk][2 * tm];
      float2 g2 = *(const float2*)&s.Gl[sub][kk][2 * tb];
      acc[0][0] += w2.x * g2.x; acc[0][1] += w2.x * g2.y;
      acc[1][0] += w2.y * g2.x; acc[1][1] += w2.y * g2.y;
    }
    __syncthreads();
  }
#pragma unroll
  for (int mm = 0; mm < 2; mm++)
#pragma unroll
    for (int b2 = 0; b2 < 2; b2++)
      dp[((size_t)by * BB + 2 * tb + b2) * DD + m0 + 2 * tm + mm] = acc[mm][b2];
}

// ---------------- phase: final LN + history + logits -------------------------
static __device__ void phase_final(SmFin& s, const float* __restrict__ tok,
                                   const float* __restrict__ dp, const float* __restrict__ hf,
                                   const float* __restrict__ fg, const float* __restrict__ fb,
                                   const float* __restrict__ fcw, const float* __restrict__ fcb,
                                   const int* __restrict__ pidx, float* __restrict__ out) {
  if (blockIdx.x >= BB) return;
  int b = blockIdx.x, tid = threadIdx.x;
  int wv = tid >> 6, lane = tid & 63;
  float psum = 0.f;
  for (int d = tid; d < DD; d += NTHR) {
    float v = tok[b * DD + d];
#pragma unroll
    for (int ss = 0; ss < 4; ss++) v += dp[(size_t)ss * (BB * DD) + b * DD + d];
    s.tl[d] = v;
    psum += v;
  }
#pragma unroll
  for (int m = 1; m < 64; m <<= 1) psum += __shfl_xor(psum, m, 64);
  if (lane == 0) s.red1[wv] = psum;
  __syncthreads();
  float mu = (s.red1[0] + s.red1[1] + s.red1[2] + s.red1[3]) * (1.0f / (float)DD);
  float vsum = 0.f;
  for (int d = tid; d < DD; d += NTHR) {
    float dd = s.tl[d] - mu;
    vsum += dd * dd;
  }
#pragma unroll
  for (int m = 1; m < 64; m <<= 1) vsum += __shfl_xor(vsum, m, 64);
  if (lane == 0) s.red2[wv] = vsum;
  __syncthreads();
  float var = (s.red2[0] + s.red2[1] + s.red2[2] + s.red2[3]) * (1.0f / (float)DD);
  float inv = rsqrtf(var + 1e-5f);
  float pi = (float)(*pidx);
  for (int d = tid; d < DD; d += NTHR) {
    float tn = (s.tl[d] - mu) * inv * fg[d] + fb[d];
    float hv = (hf[b * DD + d] * pi + tn) / (pi + 1.0f);
    s.hl[d] = hv;
    out[BB * NCi + b * DD + d] = hv;
  }
  __syncthreads();
  for (int n = wv; n < NCi; n += 4) {
    float sum = 0.f;
    for (int d = lane; d < DD; d += 64) sum += s.hl[d] * fcw[(size_t)n * DD + d];
#pragma unroll
    for (int m = 1; m < 64; m <<= 1) sum += __shfl_xor(sum, m, 64);
    if (lane == 0) out[b * NCi + n] = sum + fcb[n];
  }
}

// ---------------- init: zero barrier slots ----------------------------------
__global__ void k_zero(unsigned* bar) {
  int n = NBAR * BSTRIDE;
  for (int i = blockIdx.x * blockDim.x + threadIdx.x; i < n; i += gridDim.x * blockDim.x)
    bar[i] = 0u;
}

// ---------------- the mega-kernel -------------------------------------------
__global__ __launch_bounds__(NTHR, 2) void k_mega(
    const float* x, const float* hf, const float* patch_w, const float* patch_b,
    const float* cnn_w, const float* cnn_b, const float* bn_g, const float* bn_b,
    const float* bn_rm, const float* bn_rv, const float* cnn_st, const float* pos,
    const float* ipw, const float* cw, const float* cb1, const float* alog, const float* dtb,
    const float* dpar, const float* nw, const float* opw, const float* mcs, const float* ssm,
    const float* fcn_g, const float* fcn_b, const float* fc_w, const float* fc_b,
    const int* pidx, float* out, float* cin0, float* cin1, float* cin2, float* cin3,
    float* part, float* t0, float* t1, float* zx, float* yb, float* sq, float* dp,
    unsigned* bar) {
  __shared__ SmAll sm;

  phase_patch(x, patch_w, patch_b, cnn_st, cin0);
  gbar(bar, 0);
  phase_conv<10, 6>(sm.c, cin0, cnn_w + (size_t)0 * DD * DD * 5, part);
  gbar(bar, 1);
  phase_bnrelu(6, 1, part, cnn_b, bn_g, bn_b, bn_rm, bn_rv, 0, cin1,
               cnn_st + (size_t)1 * BB * DD * 4, pos, pidx);
  gbar(bar, 2);
  phase_conv<10, 6>(sm.c, cin1, cnn_w + (size_t)1 * DD * DD * 5, part);
  gbar(bar, 3);
  phase_bnrelu(6, 3, part, cnn_b + DD, bn_g + DD, bn_b + DD, bn_rm + DD, bn_rv + DD, 0, cin2,
               cnn_st + (size_t)2 * BB * DD * 4, pos, pidx);
  gbar(bar, 4);
  phase_conv<6, 2>(sm.c, cin2, cnn_w + (size_t)2 * DD * DD * 5, part);
  gbar(bar, 5);
  phase_bnrelu(2, 1, part, cnn_b + 2 * DD, bn_g + 2 * DD, bn_b + 2 * DD, bn_rm + 2 * DD,
               bn_rv + 2 * DD, 0, cin3, cnn_st + (size_t)3 * BB * DD * 4, pos, pidx);
  gbar(bar, 6);
  phase_conv<6, 2>(sm.c, cin3, cnn_w + (size_t)3 * DD * DD * 5, part);
  gbar(bar, 7);
  phase_bnrelu(2, 2, part, cnn_b + 3 * DD, bn_g + 3 * DD, bn_b + 3 * DD, bn_rm + 3 * DD,
               bn_rv + 3 * DD, 1, t0, nullptr, pos, pidx);
  gbar(bar, 8);

  int bi = 9;
  for (int L = 0; L < NLAYER; L++) {
    const float* rd = (L == 0) ? t0 : ((L & 1) ? t0 : t1);
    float* wr = (L & 1) ? t1 : ((L == 0) ? t1 : t0);
    phase_inproj(sm.i, ipw + (size_t)L * RIN * DD, rd, dp, (L > 0) ? 1 : 0, wr, zx, sq);
    gbar(bar, bi++);
    phase_ssm(sm.s, zx, ssm + (size_t)L * BB * NHi * HDi * DSi, mcs + (size_t)L * BB * DCONVi * 4,
              cw + (size_t)L * DCONVi * 4, cb1 + (size_t)L * DCONVi, alog + L * NHi,
              dtb + L * NHi, dpar + L * NHi, yb, sq);
    gbar(bar, bi++);
    phase_outproj(sm.o, opw + (size_t)L * DD * DIi, yb, zx, sq, nw + (size_t)L * DIi, dp);
    gbar(bar, bi++);
  }
  phase_final(sm.f, t1, dp, hf, fcn_g, fcn_b, fc_w, fc_b, pidx, out);
}

// ---------------------------------------------------------------------------
extern "C" void kernel_launch(void* const* d_in, const int* in_sizes, int n_in,
                              void* d_out, int out_size, void* d_ws, size_t ws_size,
                              hipStream_t stream) {
  const float* x       = (const float*)d_in[0];
  const float* hf      = (const float*)d_in[1];
  const float* patch_w = (const float*)d_in[2];
  const float* patch_b = (const float*)d_in[3];
  const float* cnn_w   = (const float*)d_in[4];
  const float* cnn_b   = (const float*)d_in[5];
  const float* bn_g    = (const float*)d_in[6];
  const float* bn_b    = (const float*)d_in[7];
  const float* bn_rm   = (const float*)d_in[8];
  const float* bn_rv   = (const float*)d_in[9];
  const float* cnn_st  = (const float*)d_in[10];
  const float* pos     = (const float*)d_in[11];
  const float* ipw     = (const float*)d_in[12];
  const float* cw      = (const float*)d_in[13];
  const float* cb1     = (const float*)d_in[14];
  const float* alog    = (const float*)d_in[15];
  const float* dtb     = (const float*)d_in[16];
  const float* dpar    = (const float*)d_in[17];
  const float* nw      = (const float*)d_in[18];
  const float* opw     = (const float*)d_in[19];
  const float* mcs     = (const float*)d_in[20];
  const float* ssm     = (const float*)d_in[21];
  const float* fcn_g   = (const float*)d_in[22];
  const float* fcn_b   = (const float*)d_in[23];
  const float* fc_w    = (const float*)d_in[24];
  const float* fc_b    = (const float*)d_in[25];
  const int*   pidx    = (const int*)d_in[26];
  float* out = (float*)d_out;

  unsigned* bar = (unsigned*)d_ws;
  float* fw   = (float*)d_ws + (size_t)NBAR * BSTRIDE;  // 45*1040 uints
  float* cin0 = fw;
  float* cin1 = cin0 + 245760;
  float* cin2 = cin1 + 245760;
  float* cin3 = cin2 + 147456;
  float* part = cin3 + 147456;
  float* t0   = part + 2359296;
  float* t1   = t0 + 24576;
  float* zx   = t1 + 24576;
  float* yb   = zx + 427008;
  float* sq   = yb + 49152;
  float* dp   = sq + 32;

  k_zero<<<64, 256, 0, stream>>>(bar);
  k_mega<<<NBLK, NTHR, 0, stream>>>(x, hf, patch_w, patch_b, cnn_w, cnn_b, bn_g, bn_b, bn_rm,
                                    bn_rv, cnn_st, pos, ipw, cw, cb1, alog, dtb, dpar, nw, opw,
                                    mcs, ssm, fcn_g, fcn_b, fc_w, fc_b, pidx, out, cin0, cin1,
                                    cin2, cin3, part, t0, t1, zx, yb, sq, dp, bar);
}